// Round 6
// baseline (1436.676 us; speedup 1.0000x reference)
//
#include <hip/hip_runtime.h>
#include <hip/hip_bf16.h>

#define BB 4
#define LL 2048
#define KK 48
#define HH 128
#define CFEAT 416   // 16 pos + 400 rbf
#define CHKF 32     // W_edge chunk rows staged in LDS per iteration

// Fully fused ProteinFeatures kernel, v6. One 256-thread block per (b,l) row.
// OUTPUT BUFFER IS FLOAT32 (round-0..5 forensics): E_idx (B,L,K) as f32 at
// offset 0, then E (B,L,K,H) as f32 at offset B*L*K.
__global__ __launch_bounds__(256) void pf6_fused(
    const float* __restrict__ X, const float* __restrict__ mask,
    const int* __restrict__ Ridx, const int* __restrict__ chain,
    const float* __restrict__ Wpos, const float* __restrict__ bpos,
    const float* __restrict__ Wedge, const float* __restrict__ gamma,
    const float* __restrict__ beta,
    float* __restrict__ outIdx, float* __restrict__ outEdge) {
    const int row = blockIdx.x;             // b*L + l
    const int bq = row >> 11;
    const int lq = row & (LL - 1);
    const int tid = threadIdx.x;
    const float* Xb = X + (size_t)bq * LL * 12;

    __shared__ float s_self[15];                // self 5-atom coords
    __shared__ float s_nb[KK * 15];             // neighbor 5-atom coords
    __shared__ float s_D[KK * 25];              // pairwise atom distances
    __shared__ int s_dcode[KK];
    __shared__ int s_sel[KK];
    __shared__ float s_feat[KK * (CHKF + 1)];
    __shared__ __align__(16) float s_W[CHKF * HH];
    __shared__ float s_E[KK * HH];
    __shared__ unsigned long long s_wb[4];
    __shared__ unsigned long long s_win;

    // ------------------------------------------------------------ top-k ----
    const float cax = Xb[(size_t)lq * 12 + 3];
    const float cay = Xb[(size_t)lq * 12 + 4];
    const float caz = Xb[(size_t)lq * 12 + 5];

    float dval[8];
    #pragma unroll
    for (int i = 0; i < 8; ++i) {
        int j = i * 256 + tid;
        float dx = __fadd_rn(cax, -Xb[(size_t)j * 12 + 3]);
        float dy = __fadd_rn(cay, -Xb[(size_t)j * 12 + 4]);
        float dz = __fadd_rn(caz, -Xb[(size_t)j * 12 + 5]);
        float d2 = __fadd_rn(__fadd_rn(__fmul_rn(dx, dx), __fmul_rn(dy, dy)),
                             __fmul_rn(dz, dz));
        d2 = __fadd_rn(d2, __fmul_rn(1.0f - mask[(size_t)bq * LL + j], 1.0e6f));
        dval[i] = d2;
    }

    for (int kk = 0; kk < KK; ++kk) {
        unsigned long long best = ~0ULL;
        #pragma unroll
        for (int i = 0; i < 8; ++i) {
            int j = i * 256 + tid;
            unsigned long long key =
                ((unsigned long long)__float_as_uint(dval[i]) << 32) | (unsigned int)j;
            best = key < best ? key : best;
        }
        #pragma unroll
        for (int off = 32; off > 0; off >>= 1) {
            unsigned long long o = __shfl_down(best, off, 64);
            best = o < best ? o : best;
        }
        if ((tid & 63) == 0) s_wb[tid >> 6] = best;
        __syncthreads();
        if (tid == 0) {
            unsigned long long m0 = s_wb[0] < s_wb[1] ? s_wb[0] : s_wb[1];
            unsigned long long m1 = s_wb[2] < s_wb[3] ? s_wb[2] : s_wb[3];
            unsigned long long mw = m0 < m1 ? m0 : m1;
            s_win = mw;
            s_sel[kk] = (int)(mw & 0xFFFFFFFFu);
        }
        __syncthreads();
        int jw = (int)(s_win & 0xFFFFFFFFu);
        if ((jw & 255) == tid) dval[jw >> 8] = __uint_as_float(0x7F800000u);
        __syncthreads();
    }

    if (tid < KK)
        outIdx[(size_t)row * KK + tid] = (float)s_sel[tid];

    // --------------------------------- neighbor atoms (with CB) + dcode ----
    const float KA = -0.58273431f, KB = 0.56802827f, KC = -0.54067466f;
    if (tid < KK) {
        int j = s_sel[tid];
        const float* x = Xb + (size_t)j * 12;
        float u0 = x[3] - x[0], u1 = x[4] - x[1], u2 = x[5] - x[2];
        float w0 = x[6] - x[3], w1 = x[7] - x[4], w2 = x[8] - x[5];
        float r0 = u1 * w2 - u2 * w1;
        float r1 = u2 * w0 - u0 * w2;
        float r2 = u0 * w1 - u1 * w0;
        float* o = &s_nb[tid * 15];
        #pragma unroll
        for (int t = 0; t < 12; ++t) o[t] = x[t];
        o[12] = KA * r0 + KB * u0 + KC * w0 + x[3];
        o[13] = KA * r1 + KB * u1 + KC * w1 + x[4];
        o[14] = KA * r2 + KB * u2 + KC * w2 + x[5];

        int offr = Ridx[row] - Ridx[(size_t)bq * LL + j];
        int same = (chain[row] == chain[(size_t)bq * LL + j]);
        int d = offr + 32;
        d = d < 0 ? 0 : (d > 64 ? 64 : d);
        s_dcode[tid] = same ? d : 65;
    }
    if (tid == 64) {   // self atoms on a different wave than tid<48
        const float* x = Xb + (size_t)lq * 12;
        float u0 = x[3] - x[0], u1 = x[4] - x[1], u2 = x[5] - x[2];
        float w0 = x[6] - x[3], w1 = x[7] - x[4], w2 = x[8] - x[5];
        float r0 = u1 * w2 - u2 * w1;
        float r1 = u2 * w0 - u0 * w2;
        float r2 = u0 * w1 - u1 * w0;
        #pragma unroll
        for (int t = 0; t < 12; ++t) s_self[t] = x[t];
        s_self[12] = KA * r0 + KB * u0 + KC * w0 + x[3];
        s_self[13] = KA * r1 + KB * u1 + KC * w1 + x[4];
        s_self[14] = KA * r2 + KB * u2 + KC * w2 + x[5];
    }
    __syncthreads();

    // ------------------------------------------------ pairwise distances ----
    for (int idx = tid; idx < KK * 25; idx += 256) {
        int k = idx / 25, pq = idx % 25, p = pq / 5, q = pq % 5;
        float dx = s_self[p * 3 + 0] - s_nb[k * 15 + q * 3 + 0];
        float dy = s_self[p * 3 + 1] - s_nb[k * 15 + q * 3 + 1];
        float dz = s_self[p * 3 + 2] - s_nb[k * 15 + q * 3 + 2];
        s_D[idx] = sqrtf(dx * dx + dy * dy + dz * dz + 1e-6f);
    }
    __syncthreads();

    // --------------------------------------------------- features + GEMM ----
    float acc[3][8];
    #pragma unroll
    for (int r = 0; r < 3; ++r)
        #pragma unroll
        for (int i = 0; i < 8; ++i) acc[r][i] = 0.0f;
    const int tm = tid >> 4, tn = tid & 15;

    for (int c0 = 0; c0 < CFEAT; c0 += CHKF) {   // 13 chunks of 32
        for (int idx = tid * 4; idx < CHKF * HH; idx += 1024)
            *(float4*)(s_W + idx) = *(const float4*)(Wedge + (size_t)c0 * HH + idx);
        for (int idx = tid; idx < KK * CHKF; idx += 256) {
            int k = idx >> 5, cc = idx & 31, c = c0 + cc;
            float val;
            if (c < 16) {
                val = Wpos[s_dcode[k] * 16 + c] + bpos[c];
            } else {
                int r = c - 16;
                int pq = r >> 4, m = r & 15;
                float mu = 2.0f + (4.0f / 3.0f) * (float)m;
                float tt = (s_D[k * 25 + pq] - mu) * 0.8f;
                val = expf(-tt * tt);
            }
            s_feat[k * (CHKF + 1) + cc] = val;
        }
        __syncthreads();
        #pragma unroll 4
        for (int c = 0; c < CHKF; ++c) {
            float f0 = s_feat[tm * (CHKF + 1) + c];
            float f1 = s_feat[(tm + 16) * (CHKF + 1) + c];
            float f2 = s_feat[(tm + 32) * (CHKF + 1) + c];
            float4 w0 = *(const float4*)(s_W + c * HH + tn * 8);
            float4 w1 = *(const float4*)(s_W + c * HH + tn * 8 + 4);
            float wvv[8] = {w0.x, w0.y, w0.z, w0.w, w1.x, w1.y, w1.z, w1.w};
            float fvv[3] = {f0, f1, f2};
            #pragma unroll
            for (int r = 0; r < 3; ++r)
                #pragma unroll
                for (int i = 0; i < 8; ++i) acc[r][i] += fvv[r] * wvv[i];
        }
        __syncthreads();
    }

    #pragma unroll
    for (int r = 0; r < 3; ++r) {
        int m = tm + 16 * r;
        #pragma unroll
        for (int i = 0; i < 8; ++i) s_E[m * HH + tn * 8 + i] = acc[r][i];
    }
    __syncthreads();

    // --------------------------------------------------- layernorm + store --
    const int lane = tid & 63, wq = tid >> 6;
    const float g0 = gamma[lane], g1 = gamma[64 + lane];
    const float be0 = beta[lane], be1 = beta[64 + lane];
    for (int m = wq; m < KK; m += 4) {
        float x0 = s_E[m * HH + lane];
        float x1 = s_E[m * HH + 64 + lane];
        float s = x0 + x1;
        float ss = x0 * x0 + x1 * x1;
        #pragma unroll
        for (int off = 32; off > 0; off >>= 1) {
            s += __shfl_down(s, off, 64);
            ss += __shfl_down(ss, off, 64);
        }
        s = __shfl(s, 0, 64);
        ss = __shfl(ss, 0, 64);
        float mean = s * (1.0f / 128.0f);
        float var = ss * (1.0f / 128.0f) - mean * mean;
        float inv = 1.0f / sqrtf(var + 1e-5f);
        size_t base = ((size_t)row * KK + m) * HH;
        outEdge[base + lane] = (x0 - mean) * inv * g0 + be0;
        outEdge[base + 64 + lane] = (x1 - mean) * inv * g1 + be1;
    }
}

// ---------------------------------------------------------------- launch ----
extern "C" void kernel_launch(void* const* d_in, const int* in_sizes, int n_in,
                              void* d_out, int out_size, void* d_ws, size_t ws_size,
                              hipStream_t stream) {
    const float* X     = (const float*)d_in[0];
    const float* mask  = (const float*)d_in[1];
    const int*   Ridx  = (const int*)d_in[2];
    const int*   chain = (const int*)d_in[3];
    const float* Wpos  = (const float*)d_in[4];
    const float* bpos  = (const float*)d_in[5];
    const float* Wedge = (const float*)d_in[6];
    const float* gamma = (const float*)d_in[7];
    const float* beta  = (const float*)d_in[8];

    float* outBase = (float*)d_out;
    float* outIdx  = outBase;                          // (B,L,K) as f32 values
    float* outEdge = outBase + (size_t)BB * LL * KK;   // (B,L,K,H) f32

    hipLaunchKernelGGL(pf6_fused, dim3(BB * LL), dim3(256), 0, stream,
                       X, mask, Ridx, chain, Wpos, bpos, Wedge, gamma, beta,
                       outIdx, outEdge);
}

// Round 7
// 197.872 us; speedup vs baseline: 7.2606x; 7.2606x over previous
//
#include <hip/hip_runtime.h>
#include <hip/hip_bf16.h>

#define BB 4
#define LL 2048
#define KK 48
#define HH 128
#define NRBF 400
#define KSTEPS 13          // 13 x 32 = 416 >= 400 (padded with zeros)
#define ESTR 132           // s_E row stride (f32) -- conflict-free stores
#define FSTR 40            // feat row stride (shorts) -- 2-way max on b128
#define CANDCAP 320

using bf16x8 = __attribute__((ext_vector_type(8))) short;
using f32x4  = __attribute__((ext_vector_type(4))) float;

// ---- prep 1: W_edge[16:416] -> bf16, MFMA-fragment-ready layout ------------
// Wt[(((kt*8+nt)*16+col)*4+kg)*8+j] = bf16(W_edge[16 + kt*32+kg*8+j][nt*16+col])
__global__ __launch_bounds__(256) void pf7_prep_w(const float* __restrict__ Wedge,
                                                  short* __restrict__ Wt) {
    int idx = blockIdx.x * 256 + threadIdx.x;            // 13*8*16*32 = 53248
    if (idx >= 13 * 8 * 16 * 32) return;
    int j  = idx & 7;
    int kg = (idx >> 3) & 3;
    int col = (idx >> 5) & 15;
    int nt = (idx >> 9) & 7;
    int kt = idx >> 12;
    int k = kt * 32 + kg * 8 + j;
    int n = nt * 16 + col;
    float v = (k < NRBF) ? Wedge[(size_t)(16 + k) * HH + n] : 0.0f;
    __hip_bfloat16 h = __float2bfloat16(v);
    Wt[idx] = *reinterpret_cast<short*>(&h);
}

// ---- prep 2: W_pe[d][h] = sum_p (W_pos[d][p]+b_pos[p]) * W_edge[p][h] ------
__global__ __launch_bounds__(256) void pf7_prep_pe(const float* __restrict__ Wpos,
                                                   const float* __restrict__ bpos,
                                                   const float* __restrict__ Wedge,
                                                   float* __restrict__ Wpe) {
    int idx = blockIdx.x * 256 + threadIdx.x;            // 66*128 = 8448
    if (idx >= 66 * HH) return;
    int d = idx >> 7, h = idx & 127;
    float s = 0.f;
    #pragma unroll
    for (int p = 0; p < 16; ++p)
        s += (Wpos[d * 16 + p] + bpos[p]) * Wedge[p * HH + h];
    Wpe[idx] = s;
}

// ---- main: radix-select top-k + bf16 MFMA GEMM + LN ------------------------
__global__ __launch_bounds__(256) void pf7_main(
    const float* __restrict__ X, const float* __restrict__ mask,
    const int* __restrict__ Ridx, const int* __restrict__ chain,
    const float* __restrict__ gamma, const float* __restrict__ beta,
    const short* __restrict__ Wt, const float* __restrict__ Wpe,
    float* __restrict__ outIdx, float* __restrict__ outEdge) {

    const int row = blockIdx.x;             // b*L + l
    const int bq = row >> 11, lq = row & (LL - 1);
    const int tid = threadIdx.x;
    const int lane = tid & 63, wid = tid >> 6;
    const float* Xb = X + (size_t)bq * LL * 12;

    __shared__ union {
        struct { int hist[1024]; unsigned long long cand[CANDCAP]; } p1;
        float E[KK * ESTR];
    } u;
    __shared__ float s_D[KK * 25];
    __shared__ float s_nb[KK * 15];
    __shared__ float s_self[15];
    __shared__ __align__(16) short s_feat[KK * FSTR];
    __shared__ int s_sel[KK];
    __shared__ int s_dcode[KK];
    __shared__ int s_wsum[4];
    __shared__ int s_bstar, s_cc;

    // ------------------------------------------------ top-k: distances ----
    const float cax = Xb[(size_t)lq * 12 + 3];
    const float cay = Xb[(size_t)lq * 12 + 4];
    const float caz = Xb[(size_t)lq * 12 + 5];
    float dval[8];
    #pragma unroll
    for (int i = 0; i < 8; ++i) {
        int j = i * 256 + tid;
        float dx = __fadd_rn(cax, -Xb[(size_t)j * 12 + 3]);
        float dy = __fadd_rn(cay, -Xb[(size_t)j * 12 + 4]);
        float dz = __fadd_rn(caz, -Xb[(size_t)j * 12 + 5]);
        float d2 = __fadd_rn(__fadd_rn(__fmul_rn(dx, dx), __fmul_rn(dy, dy)),
                             __fmul_rn(dz, dz));
        d2 = __fadd_rn(d2, __fmul_rn(1.0f - mask[(size_t)bq * LL + j], 1.0e6f));
        dval[i] = d2;
    }

    // ---------------------------------------- histogram on bits [31:22] ----
    #pragma unroll
    for (int t = 0; t < 4; ++t) u.p1.hist[tid * 4 + t] = 0;
    if (tid == 0) s_cc = 0;
    __syncthreads();
    #pragma unroll
    for (int i = 0; i < 8; ++i)
        atomicAdd(&u.p1.hist[__float_as_uint(dval[i]) >> 22], 1);
    __syncthreads();

    // ------------------------------------------- scan, find cutoff bin ----
    int c0 = u.p1.hist[tid * 4 + 0];
    int c1 = u.p1.hist[tid * 4 + 1];
    int c2 = u.p1.hist[tid * 4 + 2];
    int c3 = u.p1.hist[tid * 4 + 3];
    int local = c0 + c1 + c2 + c3;
    int v = local;
    #pragma unroll
    for (int off = 1; off < 64; off <<= 1) {
        int o = __shfl_up(v, off, 64);
        if (lane >= off) v += o;
    }
    if (lane == 63) s_wsum[wid] = v;
    __syncthreads();
    int woff = 0;
    #pragma unroll
    for (int w2 = 0; w2 < 4; ++w2) if (w2 < wid) woff += s_wsum[w2];
    int incl = woff + v, excl = incl - local;
    if (excl < KK && incl >= KK) {
        int cum = excl, b = tid * 4;
        if (cum + c0 >= KK) s_bstar = b;
        else { cum += c0;
            if (cum + c1 >= KK) s_bstar = b + 1;
            else { cum += c1;
                if (cum + c2 >= KK) s_bstar = b + 2;
                else s_bstar = b + 3; } }
    }
    __syncthreads();

    // ------------------------------------------------ collect candidates ----
    int bstar = s_bstar;
    #pragma unroll
    for (int i = 0; i < 8; ++i) {
        unsigned int kb = __float_as_uint(dval[i]);
        if ((int)(kb >> 22) <= bstar) {
            int pos = atomicAdd(&s_cc, 1);
            if (pos < CANDCAP)
                u.p1.cand[pos] =
                    ((unsigned long long)kb << 32) | (unsigned)(i * 256 + tid);
        }
    }
    __syncthreads();

    // ------------------------------- exact rank (ties -> lower index) ----
    int C = s_cc < CANDCAP ? s_cc : CANDCAP;
    for (int ci = tid; ci < C; ci += 256) {
        unsigned long long me = u.p1.cand[ci];
        int rank = 0;
        for (int j2 = 0; j2 < C; ++j2) rank += (u.p1.cand[j2] < me) ? 1 : 0;
        if (rank < KK) s_sel[rank] = (int)(me & 0xFFFFFFFFu);
    }
    __syncthreads();

    if (tid < KK) outIdx[(size_t)row * KK + tid] = (float)s_sel[tid];

    // --------------------------------- neighbor atoms (with CB) + dcode ----
    const float KA = -0.58273431f, KB = 0.56802827f, KC = -0.54067466f;
    if (tid < KK) {
        int j = s_sel[tid];
        const float* x = Xb + (size_t)j * 12;
        float u0 = x[3] - x[0], u1 = x[4] - x[1], u2 = x[5] - x[2];
        float w0 = x[6] - x[3], w1 = x[7] - x[4], w2 = x[8] - x[5];
        float r0 = u1 * w2 - u2 * w1;
        float r1 = u2 * w0 - u0 * w2;
        float r2 = u0 * w1 - u1 * w0;
        float* o = &s_nb[tid * 15];
        #pragma unroll
        for (int t = 0; t < 12; ++t) o[t] = x[t];
        o[12] = KA * r0 + KB * u0 + KC * w0 + x[3];
        o[13] = KA * r1 + KB * u1 + KC * w1 + x[4];
        o[14] = KA * r2 + KB * u2 + KC * w2 + x[5];
        int offr = Ridx[row] - Ridx[(size_t)bq * LL + j];
        int same = (chain[row] == chain[(size_t)bq * LL + j]);
        int d = offr + 32;
        d = d < 0 ? 0 : (d > 64 ? 64 : d);
        s_dcode[tid] = same ? d : 65;
    }
    if (tid == 64) {
        const float* x = Xb + (size_t)lq * 12;
        float u0 = x[3] - x[0], u1 = x[4] - x[1], u2 = x[5] - x[2];
        float w0 = x[6] - x[3], w1 = x[7] - x[4], w2 = x[8] - x[5];
        float r0 = u1 * w2 - u2 * w1;
        float r1 = u2 * w0 - u0 * w2;
        float r2 = u0 * w1 - u1 * w0;
        #pragma unroll
        for (int t = 0; t < 12; ++t) s_self[t] = x[t];
        s_self[12] = KA * r0 + KB * u0 + KC * w0 + x[3];
        s_self[13] = KA * r1 + KB * u1 + KC * w1 + x[4];
        s_self[14] = KA * r2 + KB * u2 + KC * w2 + x[5];
    }
    __syncthreads();

    // ------------------------------------------------ pairwise distances ----
    for (int idx = tid; idx < KK * 25; idx += 256) {
        int k = idx / 25, pq = idx % 25, p = pq / 5, q = pq % 5;
        float dx = s_self[p * 3 + 0] - s_nb[k * 15 + q * 3 + 0];
        float dy = s_self[p * 3 + 1] - s_nb[k * 15 + q * 3 + 1];
        float dz = s_self[p * 3 + 2] - s_nb[k * 15 + q * 3 + 2];
        s_D[idx] = sqrtf(dx * dx + dy * dy + dz * dz + 1e-6f);
    }
    __syncthreads();

    // -------------------------------------------- MFMA GEMM over 13 K-steps -
    f32x4 acc[3][2];
    #pragma unroll
    for (int mt = 0; mt < 3; ++mt)
        #pragma unroll
        for (int nb2 = 0; nb2 < 2; ++nb2) acc[mt][nb2] = (f32x4){0.f, 0.f, 0.f, 0.f};
    const int nt0 = wid * 2;
    const int arow = lane & 15, kg = lane >> 4;

    for (int kt = 0; kt < KSTEPS; ++kt) {
        // B fragments straight from global (L2-resident, coalesced 16B/lane)
        bf16x8 bf0 = *reinterpret_cast<const bf16x8*>(
            Wt + (((kt * 8 + nt0) * 16 + arow) * 32 + kg * 8));
        bf16x8 bf1 = *reinterpret_cast<const bf16x8*>(
            Wt + (((kt * 8 + nt0 + 1) * 16 + arow) * 32 + kg * 8));
        // features for this K-step (48 edges x 32 rbf dims, bf16)
        #pragma unroll
        for (int p = 0; p < 6; ++p) {
            int i = tid + p * 256;
            int k = i >> 5, cc = i & 31, r = kt * 32 + cc;
            float val = 0.f;
            if (r < NRBF) {
                int pq = r >> 4, m = r & 15;
                float t = (s_D[k * 25 + pq] - (2.0f + (4.0f / 3.0f) * (float)m)) * 0.8f;
                val = __expf(-t * t);
            }
            __hip_bfloat16 hb = __float2bfloat16(val);
            s_feat[k * FSTR + cc] = *reinterpret_cast<short*>(&hb);
        }
        __syncthreads();
        bf16x8 a0 = *reinterpret_cast<const bf16x8*>(&s_feat[(arow     ) * FSTR + kg * 8]);
        bf16x8 a1 = *reinterpret_cast<const bf16x8*>(&s_feat[(arow + 16) * FSTR + kg * 8]);
        bf16x8 a2 = *reinterpret_cast<const bf16x8*>(&s_feat[(arow + 32) * FSTR + kg * 8]);
        acc[0][0] = __builtin_amdgcn_mfma_f32_16x16x32_bf16(a0, bf0, acc[0][0], 0, 0, 0);
        acc[1][0] = __builtin_amdgcn_mfma_f32_16x16x32_bf16(a1, bf0, acc[1][0], 0, 0, 0);
        acc[2][0] = __builtin_amdgcn_mfma_f32_16x16x32_bf16(a2, bf0, acc[2][0], 0, 0, 0);
        acc[0][1] = __builtin_amdgcn_mfma_f32_16x16x32_bf16(a0, bf1, acc[0][1], 0, 0, 0);
        acc[1][1] = __builtin_amdgcn_mfma_f32_16x16x32_bf16(a1, bf1, acc[1][1], 0, 0, 0);
        acc[2][1] = __builtin_amdgcn_mfma_f32_16x16x32_bf16(a2, bf1, acc[2][1], 0, 0, 0);
        __syncthreads();
    }

    // ------------------------------------- write E fragments (D layout:
    // col = lane&15, row = (lane>>4)*4 + reg) --------------------------------
    #pragma unroll
    for (int mt = 0; mt < 3; ++mt)
        #pragma unroll
        for (int nb2 = 0; nb2 < 2; ++nb2)
            #pragma unroll
            for (int r = 0; r < 4; ++r)
                u.E[(mt * 16 + kg * 4 + r) * ESTR + (nt0 + nb2) * 16 + arow] =
                    acc[mt][nb2][r];
    __syncthreads();

    // --------------------------------------------------- layernorm + store --
    const float g0 = gamma[lane], g1 = gamma[64 + lane];
    const float be0 = beta[lane], be1 = beta[64 + lane];
    for (int m = wid; m < KK; m += 4) {
        const float* pe = Wpe + (size_t)s_dcode[m] * HH;
        float x0 = u.E[m * ESTR + lane] + pe[lane];
        float x1 = u.E[m * ESTR + 64 + lane] + pe[64 + lane];
        float s = x0 + x1;
        float ss = x0 * x0 + x1 * x1;
        #pragma unroll
        for (int off = 32; off > 0; off >>= 1) {
            s += __shfl_down(s, off, 64);
            ss += __shfl_down(ss, off, 64);
        }
        s = __shfl(s, 0, 64);
        ss = __shfl(ss, 0, 64);
        float mean = s * (1.0f / 128.0f);
        float var = ss * (1.0f / 128.0f) - mean * mean;
        float inv = 1.0f / sqrtf(var + 1e-5f);
        size_t base = ((size_t)row * KK + m) * HH;
        outEdge[base + lane] = (x0 - mean) * inv * g0 + be0;
        outEdge[base + 64 + lane] = (x1 - mean) * inv * g1 + be1;
    }
}

// ---------------------------------------------------------------- launch ----
extern "C" void kernel_launch(void* const* d_in, const int* in_sizes, int n_in,
                              void* d_out, int out_size, void* d_ws, size_t ws_size,
                              hipStream_t stream) {
    const float* X     = (const float*)d_in[0];
    const float* mask  = (const float*)d_in[1];
    const int*   Ridx  = (const int*)d_in[2];
    const int*   chain = (const int*)d_in[3];
    const float* Wpos  = (const float*)d_in[4];
    const float* bpos  = (const float*)d_in[5];
    const float* Wedge = (const float*)d_in[6];
    const float* gamma = (const float*)d_in[7];
    const float* beta  = (const float*)d_in[8];

    float* outBase = (float*)d_out;
    float* outIdx  = outBase;                          // (B,L,K) f32
    float* outEdge = outBase + (size_t)BB * LL * KK;   // (B,L,K,H) f32

    float* Wpe = (float*)d_ws;                         // 66*128 f32 = 33792 B
    short* Wt  = (short*)((char*)d_ws + 66 * HH * sizeof(float)); // 106496 B

    hipLaunchKernelGGL(pf7_prep_pe, dim3(33), dim3(256), 0, stream,
                       Wpos, bpos, Wedge, Wpe);
    hipLaunchKernelGGL(pf7_prep_w, dim3(208), dim3(256), 0, stream,
                       Wedge, Wt);
    hipLaunchKernelGGL(pf7_main, dim3(BB * LL), dim3(256), 0, stream,
                       X, mask, Ridx, chain, gamma, beta, Wt, Wpe,
                       outIdx, outEdge);
}

// Round 8
// 186.832 us; speedup vs baseline: 7.6897x; 1.0591x over previous
//
#include <hip/hip_runtime.h>
#include <hip/hip_bf16.h>

#define BB 4
#define LL 2048
#define KK 48
#define HH 128
#define NRBF 400
#define KSTEPS 13          // 13 x 32 = 416 >= 400 (zero-padded)
#define ESTR 132           // E row stride (f32)
#define FSTR 40            // feat row stride (shorts)
#define CANDCAP 384

using bf16x8 = __attribute__((ext_vector_type(8))) short;
using f32x4  = __attribute__((ext_vector_type(4))) float;

// ---- prep 1: W_edge[16:416] -> bf16, MFMA-fragment-ready layout ------------
__global__ __launch_bounds__(256) void pf8_prep_w(const float* __restrict__ Wedge,
                                                  short* __restrict__ Wt) {
    int idx = blockIdx.x * 256 + threadIdx.x;            // 13*8*16*32 = 53248
    if (idx >= 13 * 8 * 16 * 32) return;
    int j  = idx & 7;
    int kg = (idx >> 3) & 3;
    int col = (idx >> 5) & 15;
    int nt = (idx >> 9) & 7;
    int kt = idx >> 12;
    int k = kt * 32 + kg * 8 + j;
    int n = nt * 16 + col;
    float v = (k < NRBF) ? Wedge[(size_t)(16 + k) * HH + n] : 0.0f;
    __hip_bfloat16 h = __float2bfloat16(v);
    Wt[idx] = *reinterpret_cast<short*>(&h);
}

// ---- prep 2: W_pe[d][h] = sum_p (W_pos[d][p]+b_pos[p]) * W_edge[p][h] ------
__global__ __launch_bounds__(256) void pf8_prep_pe(const float* __restrict__ Wpos,
                                                   const float* __restrict__ bpos,
                                                   const float* __restrict__ Wedge,
                                                   float* __restrict__ Wpe) {
    int idx = blockIdx.x * 256 + threadIdx.x;            // 66*128 = 8448
    if (idx >= 66 * HH) return;
    int d = idx >> 7, h = idx & 127;
    float s = 0.f;
    #pragma unroll
    for (int p = 0; p < 16; ++p)
        s += (Wpos[d * 16 + p] + bpos[p]) * Wedge[p * HH + h];
    Wpe[idx] = s;
}

// ---- main ------------------------------------------------------------------
__global__ __launch_bounds__(256) void pf8_main(
    const float* __restrict__ X, const float* __restrict__ mask,
    const int* __restrict__ Ridx, const int* __restrict__ chain,
    const float* __restrict__ gamma, const float* __restrict__ beta,
    const short* __restrict__ Wt, const float* __restrict__ Wpe,
    float* __restrict__ outIdx, float* __restrict__ outEdge) {

    const int row = blockIdx.x;             // b*L + l
    const int bq = row >> 11, lq = row & (LL - 1);
    const int tid = threadIdx.x;
    const int lane = tid & 63, wid = tid >> 6;
    const float* Xb = X + (size_t)bq * LL * 12;

    __shared__ __align__(16) union {
        struct { int hist[1024]; unsigned long long cand[CANDCAP]; } p1; // 7168
        struct { float D[KK * 25]; float nb[KK * 15]; float self[16]; } geo; // 7744
    } u1;
    __shared__ __align__(16) union {
        short feat[2][KK * FSTR];           // 2 x 3840 B
        float E[KK * ESTR];                 // 25344 B
    } u2;
    __shared__ int s_sel[KK];
    __shared__ int s_dcode[KK];
    __shared__ int s_wsum[4];
    __shared__ int s_bstar, s_cc;

    // ------------------------------------------------ top-k: distances ----
    const float cax = Xb[(size_t)lq * 12 + 3];
    const float cay = Xb[(size_t)lq * 12 + 4];
    const float caz = Xb[(size_t)lq * 12 + 5];
    float dval[8];
    #pragma unroll
    for (int i = 0; i < 8; ++i) {
        int j = i * 256 + tid;
        float dx = __fadd_rn(cax, -Xb[(size_t)j * 12 + 3]);
        float dy = __fadd_rn(cay, -Xb[(size_t)j * 12 + 4]);
        float dz = __fadd_rn(caz, -Xb[(size_t)j * 12 + 5]);
        float d2 = __fadd_rn(__fadd_rn(__fmul_rn(dx, dx), __fmul_rn(dy, dy)),
                             __fmul_rn(dz, dz));
        d2 = __fadd_rn(d2, __fmul_rn(1.0f - mask[(size_t)bq * LL + j], 1.0e6f));
        dval[i] = d2;
    }

    #pragma unroll
    for (int t = 0; t < 4; ++t) u1.p1.hist[tid * 4 + t] = 0;
    if (tid == 0) s_cc = 0;
    __syncthreads();
    #pragma unroll
    for (int i = 0; i < 8; ++i)
        atomicAdd(&u1.p1.hist[__float_as_uint(dval[i]) >> 22], 1);
    __syncthreads();

    int c0 = u1.p1.hist[tid * 4 + 0];
    int c1 = u1.p1.hist[tid * 4 + 1];
    int c2 = u1.p1.hist[tid * 4 + 2];
    int c3 = u1.p1.hist[tid * 4 + 3];
    int local = c0 + c1 + c2 + c3;
    int v = local;
    #pragma unroll
    for (int off = 1; off < 64; off <<= 1) {
        int o = __shfl_up(v, off, 64);
        if (lane >= off) v += o;
    }
    if (lane == 63) s_wsum[wid] = v;
    __syncthreads();
    int woff = 0;
    #pragma unroll
    for (int w2 = 0; w2 < 4; ++w2) if (w2 < wid) woff += s_wsum[w2];
    int incl = woff + v, excl = incl - local;
    if (excl < KK && incl >= KK) {
        int cum = excl, b = tid * 4;
        if (cum + c0 >= KK) s_bstar = b;
        else { cum += c0;
            if (cum + c1 >= KK) s_bstar = b + 1;
            else { cum += c1;
                if (cum + c2 >= KK) s_bstar = b + 2;
                else s_bstar = b + 3; } }
    }
    __syncthreads();

    int bstar = s_bstar;
    #pragma unroll
    for (int i = 0; i < 8; ++i) {
        unsigned int kb = __float_as_uint(dval[i]);
        if ((int)(kb >> 22) <= bstar) {
            int pos = atomicAdd(&s_cc, 1);
            if (pos < CANDCAP)
                u1.p1.cand[pos] =
                    ((unsigned long long)kb << 32) | (unsigned)(i * 256 + tid);
        }
    }
    __syncthreads();

    int C = s_cc < CANDCAP ? s_cc : CANDCAP;
    for (int ci = tid; ci < C; ci += 256) {
        unsigned long long me = u1.p1.cand[ci];
        int rank = 0;
        for (int j2 = 0; j2 < C; ++j2) rank += (u1.p1.cand[j2] < me) ? 1 : 0;
        if (rank < KK) s_sel[rank] = (int)(me & 0xFFFFFFFFu);
    }
    __syncthreads();

    if (tid < KK) outIdx[(size_t)row * KK + tid] = (float)s_sel[tid];

    // --------------------------------- neighbor atoms (with CB) + dcode ----
    const float KA = -0.58273431f, KB = 0.56802827f, KC = -0.54067466f;
    if (tid < KK) {
        int j = s_sel[tid];
        const float* x = Xb + (size_t)j * 12;
        float u0 = x[3] - x[0], u1_ = x[4] - x[1], u2_ = x[5] - x[2];
        float w0 = x[6] - x[3], w1 = x[7] - x[4], w2 = x[8] - x[5];
        float r0 = u1_ * w2 - u2_ * w1;
        float r1 = u2_ * w0 - u0 * w2;
        float r2 = u0 * w1 - u1_ * w0;
        float* o = &u1.geo.nb[tid * 15];
        #pragma unroll
        for (int t = 0; t < 12; ++t) o[t] = x[t];
        o[12] = KA * r0 + KB * u0 + KC * w0 + x[3];
        o[13] = KA * r1 + KB * u1_ + KC * w1 + x[4];
        o[14] = KA * r2 + KB * u2_ + KC * w2 + x[5];
        int offr = Ridx[row] - Ridx[(size_t)bq * LL + j];
        int same = (chain[row] == chain[(size_t)bq * LL + j]);
        int d = offr + 32;
        d = d < 0 ? 0 : (d > 64 ? 64 : d);
        s_dcode[tid] = same ? d : 65;
    }
    if (tid == 64) {
        const float* x = Xb + (size_t)lq * 12;
        float u0 = x[3] - x[0], u1_ = x[4] - x[1], u2_ = x[5] - x[2];
        float w0 = x[6] - x[3], w1 = x[7] - x[4], w2 = x[8] - x[5];
        float r0 = u1_ * w2 - u2_ * w1;
        float r1 = u2_ * w0 - u0 * w2;
        float r2 = u0 * w1 - u1_ * w0;
        #pragma unroll
        for (int t = 0; t < 12; ++t) u1.geo.self[t] = x[t];
        u1.geo.self[12] = KA * r0 + KB * u0 + KC * w0 + x[3];
        u1.geo.self[13] = KA * r1 + KB * u1_ + KC * w1 + x[4];
        u1.geo.self[14] = KA * r2 + KB * u2_ + KC * w2 + x[5];
    }
    __syncthreads();

    // ------------------------------------------------ pairwise distances ----
    for (int idx = tid; idx < KK * 25; idx += 256) {
        int k = idx / 25, pq = idx % 25, p = pq / 5, q = pq % 5;
        float dx = u1.geo.self[p * 3 + 0] - u1.geo.nb[k * 15 + q * 3 + 0];
        float dy = u1.geo.self[p * 3 + 1] - u1.geo.nb[k * 15 + q * 3 + 1];
        float dz = u1.geo.self[p * 3 + 2] - u1.geo.nb[k * 15 + q * 3 + 2];
        u1.geo.D[idx] = sqrtf(dx * dx + dy * dy + dz * dz + 1e-6f);
    }
    __syncthreads();

    // ------------------------------------- feature compute (one K-step) ----
    // thread t<192: pair = t>>1 (k = pair>>1, pq_lo = pair&1), half = t&1.
    // 16 RBF values of one (k,pq) share t0; iterate m with tm -= delta.
    auto feat_compute = [&](int kt, int fb) {
        if (tid < 192) {
            int pair = tid >> 1, half = tid & 1;
            int k = pair >> 1, pq_lo = pair & 1;
            int pq = kt * 2 + pq_lo;
            bf16x8 ov;
            if (pq < 25) {
                float D = u1.geo.D[k * 25 + pq];
                float t0 = (D - 2.0f) * 0.8f;
                const float dlt = 1.06666666667f;     // (4/3)*0.8
                float tm = __builtin_fmaf(-(float)(half << 3), dlt, t0);
                #pragma unroll
                for (int mi = 0; mi < 8; ++mi) {
                    float val = __expf(-tm * tm);
                    __hip_bfloat16 hb = __float2bfloat16(val);
                    ov[mi] = *reinterpret_cast<short*>(&hb);
                    tm -= dlt;
                }
            } else {
                #pragma unroll
                for (int mi = 0; mi < 8; ++mi) ov[mi] = 0;
            }
            *reinterpret_cast<bf16x8*>(
                &u2.feat[fb][k * FSTR + pq_lo * 16 + (half << 3)]) = ov;
        }
    };

    feat_compute(0, 0);
    __syncthreads();

    // -------------------------------------------- MFMA GEMM, 13 K-steps ----
    f32x4 acc[3][2];
    #pragma unroll
    for (int mt = 0; mt < 3; ++mt)
        #pragma unroll
        for (int nb2 = 0; nb2 < 2; ++nb2) acc[mt][nb2] = (f32x4){0.f, 0.f, 0.f, 0.f};
    const int nt0 = wid * 2;
    const int arow = lane & 15, kg = lane >> 4;

    int cur = 0;
    for (int kt = 0; kt < KSTEPS; ++kt) {
        bf16x8 bf0 = *reinterpret_cast<const bf16x8*>(
            Wt + (((kt * 8 + nt0) * 16 + arow) * 32 + kg * 8));
        bf16x8 bf1 = *reinterpret_cast<const bf16x8*>(
            Wt + (((kt * 8 + nt0 + 1) * 16 + arow) * 32 + kg * 8));
        if (kt + 1 < KSTEPS) feat_compute(kt + 1, cur ^ 1);
        bf16x8 a0 = *reinterpret_cast<const bf16x8*>(&u2.feat[cur][(arow     ) * FSTR + kg * 8]);
        bf16x8 a1 = *reinterpret_cast<const bf16x8*>(&u2.feat[cur][(arow + 16) * FSTR + kg * 8]);
        bf16x8 a2 = *reinterpret_cast<const bf16x8*>(&u2.feat[cur][(arow + 32) * FSTR + kg * 8]);
        acc[0][0] = __builtin_amdgcn_mfma_f32_16x16x32_bf16(a0, bf0, acc[0][0], 0, 0, 0);
        acc[1][0] = __builtin_amdgcn_mfma_f32_16x16x32_bf16(a1, bf0, acc[1][0], 0, 0, 0);
        acc[2][0] = __builtin_amdgcn_mfma_f32_16x16x32_bf16(a2, bf0, acc[2][0], 0, 0, 0);
        acc[0][1] = __builtin_amdgcn_mfma_f32_16x16x32_bf16(a0, bf1, acc[0][1], 0, 0, 0);
        acc[1][1] = __builtin_amdgcn_mfma_f32_16x16x32_bf16(a1, bf1, acc[1][1], 0, 0, 0);
        acc[2][1] = __builtin_amdgcn_mfma_f32_16x16x32_bf16(a2, bf1, acc[2][1], 0, 0, 0);
        __syncthreads();
        cur ^= 1;
    }

    // --------- write E fragments (C layout: col=lane&15, row=(lane>>4)*4+r) -
    #pragma unroll
    for (int mt = 0; mt < 3; ++mt)
        #pragma unroll
        for (int nb2 = 0; nb2 < 2; ++nb2)
            #pragma unroll
            for (int r = 0; r < 4; ++r)
                u2.E[(mt * 16 + kg * 4 + r) * ESTR + (nt0 + nb2) * 16 + arow] =
                    acc[mt][nb2][r];
    __syncthreads();

    // --------------------------------------------------- layernorm + store --
    const float g0 = gamma[lane], g1 = gamma[64 + lane];
    const float be0 = beta[lane], be1 = beta[64 + lane];
    for (int m = wid; m < KK; m += 4) {
        const float* pe = Wpe + (size_t)s_dcode[m] * HH;
        float x0 = u2.E[m * ESTR + lane] + pe[lane];
        float x1 = u2.E[m * ESTR + 64 + lane] + pe[64 + lane];
        float s = x0 + x1;
        float ss = x0 * x0 + x1 * x1;
        #pragma unroll
        for (int off = 32; off > 0; off >>= 1) {
            s += __shfl_down(s, off, 64);
            ss += __shfl_down(ss, off, 64);
        }
        s = __shfl(s, 0, 64);
        ss = __shfl(ss, 0, 64);
        float mean = s * (1.0f / 128.0f);
        float var = ss * (1.0f / 128.0f) - mean * mean;
        float inv = 1.0f / sqrtf(var + 1e-5f);
        size_t base = ((size_t)row * KK + m) * HH;
        outEdge[base + lane] = (x0 - mean) * inv * g0 + be0;
        outEdge[base + 64 + lane] = (x1 - mean) * inv * g1 + be1;
    }
}

// ---------------------------------------------------------------- launch ----
extern "C" void kernel_launch(void* const* d_in, const int* in_sizes, int n_in,
                              void* d_out, int out_size, void* d_ws, size_t ws_size,
                              hipStream_t stream) {
    const float* X     = (const float*)d_in[0];
    const float* mask  = (const float*)d_in[1];
    const int*   Ridx  = (const int*)d_in[2];
    const int*   chain = (const int*)d_in[3];
    const float* Wpos  = (const float*)d_in[4];
    const float* bpos  = (const float*)d_in[5];
    const float* Wedge = (const float*)d_in[6];
    const float* gamma = (const float*)d_in[7];
    const float* beta  = (const float*)d_in[8];

    float* outBase = (float*)d_out;
    float* outIdx  = outBase;                          // (B,L,K) f32
    float* outEdge = outBase + (size_t)BB * LL * KK;   // (B,L,K,H) f32

    float* Wpe = (float*)d_ws;                         // 66*128 f32
    short* Wt  = (short*)((char*)d_ws + 66 * HH * sizeof(float));

    hipLaunchKernelGGL(pf8_prep_pe, dim3(33), dim3(256), 0, stream,
                       Wpos, bpos, Wedge, Wpe);
    hipLaunchKernelGGL(pf8_prep_w, dim3(208), dim3(256), 0, stream,
                       Wedge, Wt);
    hipLaunchKernelGGL(pf8_main, dim3(BB * LL), dim3(256), 0, stream,
                       X, mask, Ridx, chain, gamma, beta, Wt, Wpe,
                       outIdx, outEdge);
}